// Round 9
// baseline (237.064 us; speedup 1.0000x reference)
//
#include <hip/hip_runtime.h>
#include <hip/hip_bf16.h>
#include <cstdint>
#include <cstddef>

#define NN 4096

typedef float f32x4 __attribute__((ext_vector_type(4)));
typedef short s16x8 __attribute__((ext_vector_type(8)));

// ---------- prep: bit-plane mask maskT[chunk][d] (bit i = row sbase+i); no atomics ----------
__global__ __launch_bounds__(256) void k_prep(const float* __restrict__ K,
                                              unsigned long long* __restrict__ maskT) {
  const int lane = threadIdx.x & 63;
  const int wv = threadIdx.x >> 6;
  const int d0 = blockIdx.x * 256 + lane * 4;      // each lane owns 4 columns
  const int sbase = blockIdx.y * 256 + wv * 64;    // this wave's 64-row chunk
  const int chunk = blockIdx.y * 4 + wv;
  unsigned long long w0 = 0, w1 = 0, w2 = 0, w3 = 0;
#pragma unroll 8
  for (int i = 0; i < 64; ++i) {
    const float4 kv = *(const float4*)(K + (size_t)(sbase + i) * NN + d0);
    w0 |= ((unsigned long long)(kv.x != 0.0f)) << i;
    w1 |= ((unsigned long long)(kv.y != 0.0f)) << i;
    w2 |= ((unsigned long long)(kv.z != 0.0f)) << i;
    w3 |= ((unsigned long long)(kv.w != 0.0f)) << i;
  }
  unsigned long long* mp = maskT + (size_t)chunk * NN + d0;
  mp[0] = w0; mp[1] = w1; mp[2] = w2; mp[3] = w3;
}

// ---------- one-wave Sinkhorn, potentials form ----------
// a[j]   = S0[lane][j] (pre-scaled by 1/tau); mat[r*65+c] = S0[r][c] (pre-scaled).
// 20 alternating LSE updates of U (rows, even its) / V (cols, odd its).
// On exit mat[r*65+c] = log-normalized matrix; a is preserved.
__device__ __forceinline__ void sinkhorn_pot(const float (&a)[64], float* __restrict__ mat,
                                             float* __restrict__ p64, int lane) {
  float U = 0.f, V = 0.f;
  for (int it = 0; it < 20; ++it) {
    float t[64];
    if ((it & 1) == 0) {                 // row pass: U[lane] = LSE_j(a[j] - V[j])
      p64[lane] = V;
      asm volatile("s_waitcnt lgkmcnt(0)" ::: "memory");
#pragma unroll
      for (int j = 0; j < 64; ++j) t[j] = a[j] - p64[j];
    } else {                             // col pass: V[lane] = LSE_i(S0[i][lane] - U[i])
      p64[lane] = U;
      asm volatile("s_waitcnt lgkmcnt(0)" ::: "memory");
#pragma unroll
      for (int j = 0; j < 64; ++j) t[j] = mat[j * 65 + lane] - p64[j];
    }
    float m0 = t[0], m1 = t[1], m2 = t[2], m3 = t[3];
#pragma unroll
    for (int j = 4; j < 64; j += 4) {
      m0 = fmaxf(m0, t[j]);     m1 = fmaxf(m1, t[j + 1]);
      m2 = fmaxf(m2, t[j + 2]); m3 = fmaxf(m3, t[j + 3]);
    }
    const float mx = fmaxf(fmaxf(m0, m1), fmaxf(m2, m3));
    float s0 = 0.f, s1 = 0.f, s2 = 0.f, s3 = 0.f;
#pragma unroll
    for (int j = 0; j < 64; j += 4) {
      s0 += __expf(t[j] - mx);     s1 += __expf(t[j + 1] - mx);
      s2 += __expf(t[j + 2] - mx); s3 += __expf(t[j + 3] - mx);
    }
    const float lse = mx + __logf((s0 + s1) + (s2 + s3));
    if ((it & 1) == 0) U = lse; else V = lse;
  }
  p64[lane] = V;
  asm volatile("s_waitcnt lgkmcnt(0)" ::: "memory");
#pragma unroll
  for (int j = 0; j < 64; ++j) mat[lane * 65 + j] = a[j] - U - p64[j];
  asm volatile("s_waitcnt lgkmcnt(0)" ::: "memory");
}

// ---------- layer-0 transform: deg from maskT popcounts, disv, g hi/lo, xselfT ----------
__global__ __launch_bounds__(256) void k_xform0(const float* __restrict__ K,
    const unsigned long long* __restrict__ maskT,
    const float* __restrict__ cw, const float* __restrict__ cb,
    const float* __restrict__ sw, const float* __restrict__ sb,
    float* __restrict__ disv,
    __hip_bfloat16* __restrict__ gHi, __hip_bfloat16* __restrict__ gLo,
    float* __restrict__ xselfT) {
  __shared__ float pdeg[4][64];
  const int lane = threadIdx.x & 63;
  const int wv = threadIdx.x >> 6;
  const int s = blockIdx.x * 64 + lane;
  unsigned cnt = 0;
#pragma unroll
  for (int q = 0; q < 16; ++q)
    cnt += (unsigned)__popcll(maskT[(size_t)(wv * 16 + q) * NN + s]);
  pdeg[wv][lane] = (float)cnt;
  __syncthreads();
  const float ds = rsqrtf(pdeg[0][lane] + pdeg[1][lane] + pdeg[2][lane] + pdeg[3][lane]);
  if (wv == 0) disv[s] = ds;
  const float xv = K[(size_t)s * NN + s];          // diag(K)
#pragma unroll
  for (int i = 0; i < 16; ++i) {
    const int c = wv * 16 + i;
    const float gv = ds * xv * cw[c];
    const __hip_bfloat16 hi = __float2bfloat16(gv);
    gHi[(size_t)c * NN + s] = hi;
    gLo[(size_t)c * NN + s] = __float2bfloat16(gv - __bfloat162float(hi));
    xselfT[(size_t)c * NN + s] = xv * sw[c] + sb[c] + cb[c];
  }
}

// ---------- fused layer transform: wave0 sinkhorn ∥ waves1-4 FMA; rank-1 sk fold ----------
// grid (64, 2): blockIdx.x = s-tile, blockIdx.y = 32-channel half. 320 threads (5 waves).
__global__ __launch_bounds__(320, 1) void k_xform(const float* __restrict__ vT,
    const float* __restrict__ xoutT, const float* __restrict__ disv,
    const float* __restrict__ cw, const float* __restrict__ cb,
    const float* __restrict__ sw, const float* __restrict__ sb,
    __hip_bfloat16* __restrict__ gHi, __hip_bfloat16* __restrict__ gLo,
    float* __restrict__ xselfT) {
  __shared__ float skl[64 * 65];                   // sinkhorn matrix -> log sk
  __shared__ float p64[64];
  __shared__ float xt[64][64];                     // raw xout (no sk added)
  __shared__ float wcl[64 * 32], wsl[64 * 32];     // [k][c-local]
  const int tid = threadIdx.x;
  const int lane = tid & 63;
  const int wv = tid >> 6;                         // 0..4
  const int s = blockIdx.x * 64 + lane;
  const int cbase = blockIdx.y * 32;
  float a[64];
  if (wv == 0) {                                   // load + fill sinkhorn matrix
#pragma unroll
    for (int j = 0; j < 64; ++j) {
      a[j] = vT[j * 64 + lane] * 20.0f;            // S0[lane][j], coalesced
      skl[lane * 65 + j] = a[j];
    }
  } else {                                         // stage xt rows + weight slab
    const int w = wv - 1;
#pragma unroll
    for (int r = 0; r < 16; ++r)
      xt[w * 16 + r][lane] = xoutT[(size_t)(w * 16 + r) * NN + s];
#pragma unroll
    for (int q = 0; q < 8; ++q) {
      const int e = w * 512 + q * 64 + lane;       // e = k*32 + cl
      const int k = e >> 5, cl = e & 31;
      wcl[e] = cw[k * 64 + cbase + cl];
      wsl[e] = sw[k * 64 + cbase + cl];
    }
  }
  __syncthreads();                                 // B0: xt + weights staged
  float accC[8], accS[8], csum[8], ssum[8];
  if (wv == 0) {
    sinkhorn_pot(a, skl, p64, lane);               // ~9 us, no barriers inside
  } else {
    const int cl0 = (wv - 1) * 8;
#pragma unroll
    for (int i = 0; i < 8; ++i) { accC[i] = 0.f; accS[i] = 0.f; csum[i] = 0.f; ssum[i] = 0.f; }
    for (int k = 0; k < 64; ++k) {
      const float xv = xt[k][lane];
#pragma unroll
      for (int i = 0; i < 8; ++i) {
        const float wc = wcl[k * 32 + cl0 + i];    // broadcast LDS read
        const float ws_ = wsl[k * 32 + cl0 + i];
        accC[i] = fmaf(xv, wc, accC[i]);  csum[i] += wc;
        accS[i] = fmaf(xv, ws_, accS[i]); ssum[i] += ws_;
      }
    }
  }
  __syncthreads();                                 // B1: skl = log sk ready
  if (wv > 0) {
    const float skv = __expf(skl[blockIdx.x * 65 + lane]);   // sk[s>>6][s&63]
    const float ds = disv[s];
    const int cl0 = (wv - 1) * 8;
#pragma unroll
    for (int i = 0; i < 8; ++i) {
      const int c = cbase + cl0 + i;
      const float gv = ds * (accC[i] + skv * csum[i]);       // rank-1 sk fold
      const __hip_bfloat16 hi = __float2bfloat16(gv);
      gHi[(size_t)c * NN + s] = hi;
      gLo[(size_t)c * NN + s] = __float2bfloat16(gv - __bfloat162float(hi));
      xselfT[(size_t)c * NN + s] = accS[i] + skv * ssum[i] + sb[c] + cb[c];
    }
  }
}

// ---------- MFMA masked aggregation, full K per block, in-block combine ----------
__global__ __launch_bounds__(512) void k_agg(const unsigned long long* __restrict__ maskT,
    const __hip_bfloat16* __restrict__ gHi, const __hip_bfloat16* __restrict__ gLo,
    const float* __restrict__ xselfT, const float* __restrict__ disv,
    const float* __restrict__ kw, const float* __restrict__ kb,
    float* __restrict__ xoutT, float* __restrict__ vT) {
  const int tid = threadIdx.x;
  const int lane = tid & 63;
  const int wv = tid >> 6;           // 0..7
  const int mtile = wv & 3;          // channel 16-group
  const int ks = wv >> 2;            // K-split 0/1
  const int l15 = lane & 15;
  const int h = lane >> 4;           // 0..3
  const int d = blockIdx.x * 16 + l15;
  const int ch = mtile * 16 + l15;   // A-operand row (channel)
  const short* __restrict__ gh = (const short*)gHi;
  const short* __restrict__ gl = (const short*)gLo;
  f32x4 acch = {0.f, 0.f, 0.f, 0.f};
  f32x4 accl = {0.f, 0.f, 0.f, 0.f};
  const int c0 = ks * 32;
#pragma unroll 4
  for (int c = c0; c < c0 + 32; ++c) {
    const unsigned long long w = maskT[(size_t)c * NN + d];
    const unsigned half0 = (unsigned)w, half1 = (unsigned)(w >> 32);
#pragma unroll
    for (int t = 0; t < 2; ++t) {
      const unsigned half = t ? half1 : half0;
      const unsigned hb = (half >> (8 * h)) & 0xFFu;
      s16x8 bfr;
#pragma unroll
      for (int j = 0; j < 8; ++j)
        bfr[j] = (short)(((hb >> j) & 1u) * 0x3F80u);   // bit -> bf16 1.0/0.0
      const size_t abase = (size_t)ch * NN + (size_t)(c * 64 + t * 32 + 8 * h);
      const s16x8 ah = *(const s16x8*)(gh + abase);
      const s16x8 al = *(const s16x8*)(gl + abase);
      acch = __builtin_amdgcn_mfma_f32_16x16x32_bf16(ah, bfr, acch, 0, 0, 0);
      accl = __builtin_amdgcn_mfma_f32_16x16x32_bf16(al, bfr, accl, 0, 0, 0);
    }
  }
  __shared__ float rbuf[4][64][5];
  __shared__ float vred[16][17];
  f32x4 tot;
#pragma unroll
  for (int r = 0; r < 4; ++r) tot[r] = acch[r] + accl[r];
  if (ks == 1) {
#pragma unroll
    for (int r = 0; r < 4; ++r) rbuf[mtile][lane][r] = tot[r];
  }
  __syncthreads();
  if (ks == 0) {
    // C/D layout: col = lane&15 (=d), row = (lane>>4)*4 + reg (=channel in mtile)
    const float dd = disv[d];
    float p = 0.f;
#pragma unroll
    for (int r = 0; r < 4; ++r) {
      const int chr = mtile * 16 + h * 4 + r;
      const float xo = xselfT[(size_t)chr * NN + d] + dd * (tot[r] + rbuf[mtile][lane][r]);
      xoutT[(size_t)chr * NN + d] = xo;
      p = fmaf(xo, kw[chr], p);
    }
    vred[l15][mtile * 4 + h] = p;
  }
  __syncthreads();
  if (tid < 16) {
    float sum = kb[0];
#pragma unroll
    for (int q = 0; q < 16; ++q) sum += vred[tid][q];
    const int d2 = blockIdx.x * 16 + tid;
    vT[(d2 & 63) * 64 + (d2 >> 6)] = sum;          // transposed: coalesced sinkhorn load
  }
}

// ---------- final: [wave0 sinkhorn(v2) ∥ waves1-7 score matvec] -> sinkhorn -> out ----------
__global__ __launch_bounds__(512, 1) void k_final(const float* __restrict__ vT,
    const float* __restrict__ xoutT, const float* __restrict__ fw,
    const float* __restrict__ fb, float* __restrict__ out) {
  __shared__ float skl[64 * 65];                   // sk2 matrix -> log
  __shared__ float scp[64 * 65];                   // scores matrix S0[i1][i2]
  __shared__ float p64[64];
  __shared__ float sumw_sh;
  const int tid = threadIdx.x;
  const int lane = tid & 63;
  const int wv = tid >> 6;                         // 0..7
  float a[64];
  if (wv == 0) {
#pragma unroll
    for (int j = 0; j < 64; ++j) {
      a[j] = vT[j * 64 + lane] * 20.0f;
      skl[lane * 65 + j] = a[j];
    }
    sinkhorn_pot(a, skl, p64, lane);               // sk2 (log), overlapped with scores
  } else {
    const float fbv = fb[0];
    float sumw = 0.f;
#pragma unroll
    for (int k = 0; k < 64; ++k) sumw += fw[k];
    for (int n = (wv - 1) * 64 + lane; n < NN; n += 448) {
      float acc = fbv;
#pragma unroll 8
      for (int k = 0; k < 64; ++k) acc = fmaf(xoutT[(size_t)k * NN + n], fw[k], acc);
      scp[(n & 63) * 65 + (n >> 6)] = acc;         // S[i1=n&63][i2=n>>6], base only
    }
    if (tid == 64) sumw_sh = sumw;
  }
  __syncthreads();                                 // B1: skl log + scp base + sumw ready
  const float sumw = sumw_sh;
  for (int n = tid; n < NN; n += 512) {            // add sk2 term, scale by 1/tau
    const float sk2 = __expf(skl[(n >> 6) * 65 + (n & 63)]);
    const int slot = (n & 63) * 65 + (n >> 6);
    scp[slot] = (scp[slot] + sk2 * sumw) * 20.0f;
  }
  __syncthreads();                                 // B2: scp = scaled S0
  if (wv == 0) {
    float a2[64];
#pragma unroll
    for (int j = 0; j < 64; ++j) a2[j] = scp[lane * 65 + j];
    sinkhorn_pot(a2, scp, p64, lane);              // final sinkhorn (log in scp)
  }
  __syncthreads();                                 // B3
#pragma unroll
  for (int q = 0; q < 8; ++q) {
    const int e = q * 512 + tid;                   // out[i1*64+i2]
    out[e] = __expf(scp[(e >> 6) * 65 + (e & 63)]);
  }
}

extern "C" void kernel_launch(void* const* d_in, const int* in_sizes, int n_in,
                              void* d_out, int out_size, void* d_ws, size_t ws_size,
                              hipStream_t stream) {
  const float* K = (const float*)d_in[0];
  const float* cw[3] = {(const float*)d_in[4],  (const float*)d_in[10], (const float*)d_in[16]};
  const float* cb[3] = {(const float*)d_in[5],  (const float*)d_in[11], (const float*)d_in[17]};
  const float* sw[3] = {(const float*)d_in[6],  (const float*)d_in[12], (const float*)d_in[18]};
  const float* sb[3] = {(const float*)d_in[7],  (const float*)d_in[13], (const float*)d_in[19]};
  const float* kw[3] = {(const float*)d_in[8],  (const float*)d_in[14], (const float*)d_in[20]};
  const float* kb[3] = {(const float*)d_in[9],  (const float*)d_in[15], (const float*)d_in[21]};
  const float* fw = (const float*)d_in[22];
  const float* fb = (const float*)d_in[23];
  float* out = (float*)d_out;

  char* ws = (char*)d_ws;
  const size_t KB = 1024, MB = 1024 * 1024;
  float* disv               = (float*)(ws + 0);                   // 16 KB
  float* vT                 = (float*)(ws + 32 * KB);             // 16 KB
  unsigned long long* maskT = (unsigned long long*)(ws + 64 * KB);// 2 MB
  __hip_bfloat16* gHi       = (__hip_bfloat16*)(ws + 64 * KB + 2 * MB);            // 512 KB
  __hip_bfloat16* gLo       = (__hip_bfloat16*)(ws + 64 * KB + 2 * MB + 512 * KB); // 512 KB
  float* xselfT             = (float*)(ws + 64 * KB + 3 * MB);    // 1 MB
  float* xoutT              = (float*)(ws + 64 * KB + 4 * MB);    // 1 MB
  (void)in_sizes; (void)n_in; (void)out_size; (void)ws_size;

  k_prep<<<dim3(16, 16), 256, 0, stream>>>(K, maskT);
  k_xform0<<<64, 256, 0, stream>>>(K, maskT, cw[0], cb[0], sw[0], sb[0],
                                   disv, gHi, gLo, xselfT);
  k_agg<<<256, 512, 0, stream>>>(maskT, gHi, gLo, xselfT, disv, kw[0], kb[0], xoutT, vT);
  for (int l = 1; l < 3; ++l) {
    k_xform<<<dim3(64, 2), 320, 0, stream>>>(vT, xoutT, disv, cw[l], cb[l], sw[l], sb[l],
                                             gHi, gLo, xselfT);
    k_agg<<<256, 512, 0, stream>>>(maskT, gHi, gLo, xselfT, disv, kw[l], kb[l], xoutT, vT);
  }
  k_final<<<1, 512, 0, stream>>>(vT, xoutT, fw, fb, out);
}

// Round 10
// 235.737 us; speedup vs baseline: 1.0056x; 1.0056x over previous
//
#include <hip/hip_runtime.h>
#include <hip/hip_bf16.h>
#include <cstdint>
#include <cstddef>

#define NN 4096

typedef float f32x4 __attribute__((ext_vector_type(4)));
typedef short s16x8 __attribute__((ext_vector_type(8)));

// ---------- prep: bit-plane mask maskT[chunk][d] (bit i = row sbase+i); no atomics ----------
__global__ __launch_bounds__(256) void k_prep(const float* __restrict__ K,
                                              unsigned long long* __restrict__ maskT) {
  const int lane = threadIdx.x & 63;
  const int wv = threadIdx.x >> 6;
  const int d0 = blockIdx.x * 256 + lane * 4;      // each lane owns 4 columns
  const int sbase = blockIdx.y * 256 + wv * 64;    // this wave's 64-row chunk
  const int chunk = blockIdx.y * 4 + wv;
  unsigned long long w0 = 0, w1 = 0, w2 = 0, w3 = 0;
#pragma unroll 8
  for (int i = 0; i < 64; ++i) {
    const float4 kv = *(const float4*)(K + (size_t)(sbase + i) * NN + d0);
    w0 |= ((unsigned long long)(kv.x != 0.0f)) << i;
    w1 |= ((unsigned long long)(kv.y != 0.0f)) << i;
    w2 |= ((unsigned long long)(kv.z != 0.0f)) << i;
    w3 |= ((unsigned long long)(kv.w != 0.0f)) << i;
  }
  unsigned long long* mp = maskT + (size_t)chunk * NN + d0;
  mp[0] = w0; mp[1] = w1; mp[2] = w2; mp[3] = w3;
}

// ---------- one-wave Sinkhorn, potentials form, LDS-fed (no persistent reg array) ----------
// mat[r*65+c] = S0[r][c] pre-scaled by 1/tau. 20 alternating LSE updates of U/V.
// On exit mat[r*65+c] = log-normalized matrix. Live regs ~ t[64] only (no spill at 128).
__device__ __forceinline__ void sinkhorn_pot(float* __restrict__ mat,
                                             float* __restrict__ p64, int lane) {
  float U = 0.f, V = 0.f;
  for (int it = 0; it < 20; ++it) {
    p64[lane] = ((it & 1) == 0) ? V : U;
    asm volatile("s_waitcnt lgkmcnt(0)" ::: "memory");
    float t[64];
    if ((it & 1) == 0) {                 // row pass: U[lane] = LSE_j(S0[lane][j] - V[j])
#pragma unroll
      for (int j = 0; j < 64; ++j) t[j] = mat[lane * 65 + j] - p64[j];
    } else {                             // col pass: V[lane] = LSE_i(S0[i][lane] - U[i])
#pragma unroll
      for (int j = 0; j < 64; ++j) t[j] = mat[j * 65 + lane] - p64[j];
    }
    float m0 = t[0], m1 = t[1], m2 = t[2], m3 = t[3];
#pragma unroll
    for (int j = 4; j < 64; j += 4) {
      m0 = fmaxf(m0, t[j]);     m1 = fmaxf(m1, t[j + 1]);
      m2 = fmaxf(m2, t[j + 2]); m3 = fmaxf(m3, t[j + 3]);
    }
    const float mx = fmaxf(fmaxf(m0, m1), fmaxf(m2, m3));
    float s0 = 0.f, s1 = 0.f, s2 = 0.f, s3 = 0.f;
#pragma unroll
    for (int j = 0; j < 64; j += 4) {
      s0 += __expf(t[j] - mx);     s1 += __expf(t[j + 1] - mx);
      s2 += __expf(t[j + 2] - mx); s3 += __expf(t[j + 3] - mx);
    }
    const float lse = mx + __logf((s0 + s1) + (s2 + s3));
    if ((it & 1) == 0) U = lse; else V = lse;
  }
  p64[lane] = V;
  asm volatile("s_waitcnt lgkmcnt(0)" ::: "memory");
#pragma unroll
  for (int j = 0; j < 64; ++j) mat[lane * 65 + j] -= (U + p64[j]);
  asm volatile("s_waitcnt lgkmcnt(0)" ::: "memory");
}

// ---------- layer-0 transform: deg from maskT popcounts, disv, g hi/lo, xselfT ----------
__global__ __launch_bounds__(256) void k_xform0(const float* __restrict__ K,
    const unsigned long long* __restrict__ maskT,
    const float* __restrict__ cw, const float* __restrict__ cb,
    const float* __restrict__ sw, const float* __restrict__ sb,
    float* __restrict__ disv,
    __hip_bfloat16* __restrict__ gHi, __hip_bfloat16* __restrict__ gLo,
    float* __restrict__ xselfT) {
  __shared__ float pdeg[4][64];
  const int lane = threadIdx.x & 63;
  const int wv = threadIdx.x >> 6;
  const int s = blockIdx.x * 64 + lane;
  unsigned cnt = 0;
#pragma unroll
  for (int q = 0; q < 16; ++q)
    cnt += (unsigned)__popcll(maskT[(size_t)(wv * 16 + q) * NN + s]);
  pdeg[wv][lane] = (float)cnt;
  __syncthreads();
  const float ds = rsqrtf(pdeg[0][lane] + pdeg[1][lane] + pdeg[2][lane] + pdeg[3][lane]);
  if (wv == 0) disv[s] = ds;
  const float xv = K[(size_t)s * NN + s];          // diag(K)
#pragma unroll
  for (int i = 0; i < 16; ++i) {
    const int c = wv * 16 + i;
    const float gv = ds * xv * cw[c];
    const __hip_bfloat16 hi = __float2bfloat16(gv);
    gHi[(size_t)c * NN + s] = hi;
    gLo[(size_t)c * NN + s] = __float2bfloat16(gv - __bfloat162float(hi));
    xselfT[(size_t)c * NN + s] = xv * sw[c] + sb[c] + cb[c];
  }
}

// ---------- fused layer transform: wave0 sinkhorn ∥ waves1-4 FMA; rank-1 sk fold ----------
// grid (64, 2): blockIdx.x = s-tile, blockIdx.y = 32-channel half. 320 threads (5 waves).
__global__ __launch_bounds__(320, 1) void k_xform(const float* __restrict__ vT,
    const float* __restrict__ xoutT, const float* __restrict__ disv,
    const float* __restrict__ cw, const float* __restrict__ cb,
    const float* __restrict__ sw, const float* __restrict__ sb,
    __hip_bfloat16* __restrict__ gHi, __hip_bfloat16* __restrict__ gLo,
    float* __restrict__ xselfT) {
  __shared__ float skl[64 * 65];                   // sinkhorn matrix -> log sk
  __shared__ float p64[64];
  __shared__ float xt[64][64];                     // raw xout (no sk added)
  __shared__ float wcl[64 * 32], wsl[64 * 32];     // [k][c-local]
  const int tid = threadIdx.x;
  const int lane = tid & 63;
  const int wv = tid >> 6;                         // 0..4
  const int s = blockIdx.x * 64 + lane;
  const int cbase = blockIdx.y * 32;
  if (wv == 0) {                                   // fill sinkhorn matrix (coalesced)
#pragma unroll
    for (int j = 0; j < 64; ++j)
      skl[lane * 65 + j] = vT[j * 64 + lane] * 20.0f;   // S0[lane][j]
  } else {                                         // stage xt rows + weight slab
    const int w = wv - 1;
#pragma unroll
    for (int r = 0; r < 16; ++r)
      xt[w * 16 + r][lane] = xoutT[(size_t)(w * 16 + r) * NN + s];
#pragma unroll
    for (int q = 0; q < 8; ++q) {
      const int e = w * 512 + q * 64 + lane;       // e = k*32 + cl
      const int k = e >> 5, cl = e & 31;
      wcl[e] = cw[k * 64 + cbase + cl];
      wsl[e] = sw[k * 64 + cbase + cl];
    }
  }
  __syncthreads();                                 // B0: xt + weights staged
  float accC[8], accS[8], csum[8], ssum[8];
  if (wv == 0) {
    sinkhorn_pot(skl, p64, lane);                  // LDS-fed, no spills
  } else {
    const int cl0 = (wv - 1) * 8;
#pragma unroll
    for (int i = 0; i < 8; ++i) { accC[i] = 0.f; accS[i] = 0.f; csum[i] = 0.f; ssum[i] = 0.f; }
    for (int k = 0; k < 64; ++k) {
      const float xv = xt[k][lane];
#pragma unroll
      for (int i = 0; i < 8; ++i) {
        const float wc = wcl[k * 32 + cl0 + i];    // broadcast LDS read
        const float ws_ = wsl[k * 32 + cl0 + i];
        accC[i] = fmaf(xv, wc, accC[i]);  csum[i] += wc;
        accS[i] = fmaf(xv, ws_, accS[i]); ssum[i] += ws_;
      }
    }
  }
  __syncthreads();                                 // B1: skl = log sk ready
  if (wv > 0) {
    const float skv = __expf(skl[blockIdx.x * 65 + lane]);   // sk[s>>6][s&63]
    const float ds = disv[s];
    const int cl0 = (wv - 1) * 8;
#pragma unroll
    for (int i = 0; i < 8; ++i) {
      const int c = cbase + cl0 + i;
      const float gv = ds * (accC[i] + skv * csum[i]);       // rank-1 sk fold
      const __hip_bfloat16 hi = __float2bfloat16(gv);
      gHi[(size_t)c * NN + s] = hi;
      gLo[(size_t)c * NN + s] = __float2bfloat16(gv - __bfloat162float(hi));
      xselfT[(size_t)c * NN + s] = accS[i] + skv * ssum[i] + sb[c] + cb[c];
    }
  }
}

// ---------- MFMA masked aggregation, full K per block, in-block combine ----------
__global__ __launch_bounds__(512) void k_agg(const unsigned long long* __restrict__ maskT,
    const __hip_bfloat16* __restrict__ gHi, const __hip_bfloat16* __restrict__ gLo,
    const float* __restrict__ xselfT, const float* __restrict__ disv,
    const float* __restrict__ kw, const float* __restrict__ kb,
    float* __restrict__ xoutT, float* __restrict__ vT) {
  const int tid = threadIdx.x;
  const int lane = tid & 63;
  const int wv = tid >> 6;           // 0..7
  const int mtile = wv & 3;          // channel 16-group
  const int ks = wv >> 2;            // K-split 0/1
  const int l15 = lane & 15;
  const int h = lane >> 4;           // 0..3
  const int d = blockIdx.x * 16 + l15;
  const int ch = mtile * 16 + l15;   // A-operand row (channel)
  const short* __restrict__ gh = (const short*)gHi;
  const short* __restrict__ gl = (const short*)gLo;
  f32x4 acch = {0.f, 0.f, 0.f, 0.f};
  f32x4 accl = {0.f, 0.f, 0.f, 0.f};
  const int c0 = ks * 32;
#pragma unroll 4
  for (int c = c0; c < c0 + 32; ++c) {
    const unsigned long long w = maskT[(size_t)c * NN + d];
    const unsigned half0 = (unsigned)w, half1 = (unsigned)(w >> 32);
#pragma unroll
    for (int t = 0; t < 2; ++t) {
      const unsigned half = t ? half1 : half0;
      const unsigned hb = (half >> (8 * h)) & 0xFFu;
      s16x8 bfr;
#pragma unroll
      for (int j = 0; j < 8; ++j)
        bfr[j] = (short)(((hb >> j) & 1u) * 0x3F80u);   // bit -> bf16 1.0/0.0
      const size_t abase = (size_t)ch * NN + (size_t)(c * 64 + t * 32 + 8 * h);
      const s16x8 ah = *(const s16x8*)(gh + abase);
      const s16x8 al = *(const s16x8*)(gl + abase);
      acch = __builtin_amdgcn_mfma_f32_16x16x32_bf16(ah, bfr, acch, 0, 0, 0);
      accl = __builtin_amdgcn_mfma_f32_16x16x32_bf16(al, bfr, accl, 0, 0, 0);
    }
  }
  __shared__ float rbuf[4][64][5];
  __shared__ float vred[16][17];
  f32x4 tot;
#pragma unroll
  for (int r = 0; r < 4; ++r) tot[r] = acch[r] + accl[r];
  if (ks == 1) {
#pragma unroll
    for (int r = 0; r < 4; ++r) rbuf[mtile][lane][r] = tot[r];
  }
  __syncthreads();
  if (ks == 0) {
    // C/D layout: col = lane&15 (=d), row = (lane>>4)*4 + reg (=channel in mtile)
    const float dd = disv[d];
    float p = 0.f;
#pragma unroll
    for (int r = 0; r < 4; ++r) {
      const int chr = mtile * 16 + h * 4 + r;
      const float xo = xselfT[(size_t)chr * NN + d] + dd * (tot[r] + rbuf[mtile][lane][r]);
      xoutT[(size_t)chr * NN + d] = xo;
      p = fmaf(xo, kw[chr], p);
    }
    vred[l15][mtile * 4 + h] = p;
  }
  __syncthreads();
  if (tid < 16) {
    float sum = kb[0];
#pragma unroll
    for (int q = 0; q < 16; ++q) sum += vred[tid][q];
    const int d2 = blockIdx.x * 16 + tid;
    vT[(d2 & 63) * 64 + (d2 >> 6)] = sum;          // transposed: coalesced sinkhorn load
  }
}

// ---------- final: [wave0 sinkhorn(v2) ∥ waves1-7 score matvec] -> sinkhorn -> out ----------
__global__ __launch_bounds__(512, 1) void k_final(const float* __restrict__ vT,
    const float* __restrict__ xoutT, const float* __restrict__ fw,
    const float* __restrict__ fb, float* __restrict__ out) {
  __shared__ float skl[64 * 65];                   // sk2 matrix -> log
  __shared__ float scp[64 * 65];                   // scores matrix S0[i1][i2]
  __shared__ float p64[64];
  __shared__ float sumw_sh;
  const int tid = threadIdx.x;
  const int lane = tid & 63;
  const int wv = tid >> 6;                         // 0..7
  if (wv == 0) {
#pragma unroll
    for (int j = 0; j < 64; ++j)
      skl[lane * 65 + j] = vT[j * 64 + lane] * 20.0f;
    sinkhorn_pot(skl, p64, lane);                  // sk2 (log), overlapped with scores
  } else {
    const float fbv = fb[0];
    float sumw = 0.f;
#pragma unroll
    for (int k = 0; k < 64; ++k) sumw += fw[k];
    for (int n = (wv - 1) * 64 + lane; n < NN; n += 448) {
      float acc = fbv;
#pragma unroll 8
      for (int k = 0; k < 64; ++k) acc = fmaf(xoutT[(size_t)k * NN + n], fw[k], acc);
      scp[(n & 63) * 65 + (n >> 6)] = acc;         // S[i1=n&63][i2=n>>6], base only
    }
    if (tid == 64) sumw_sh = sumw;
  }
  __syncthreads();                                 // B1: skl log + scp base + sumw ready
  const float sumw = sumw_sh;
  for (int n = tid; n < NN; n += 512) {            // add sk2 term, scale by 1/tau
    const float sk2 = __expf(skl[(n >> 6) * 65 + (n & 63)]);
    const int slot = (n & 63) * 65 + (n >> 6);
    scp[slot] = (scp[slot] + sk2 * sumw) * 20.0f;
  }
  __syncthreads();                                 // B2: scp = scaled S0
  if (wv == 0) sinkhorn_pot(scp, p64, lane);       // final sinkhorn (log in scp)
  __syncthreads();                                 // B3
#pragma unroll
  for (int q = 0; q < 8; ++q) {
    const int e = q * 512 + tid;                   // out[i1*64+i2]
    out[e] = __expf(scp[(e >> 6) * 65 + (e & 63)]);
  }
}

extern "C" void kernel_launch(void* const* d_in, const int* in_sizes, int n_in,
                              void* d_out, int out_size, void* d_ws, size_t ws_size,
                              hipStream_t stream) {
  const float* K = (const float*)d_in[0];
  const float* cw[3] = {(const float*)d_in[4],  (const float*)d_in[10], (const float*)d_in[16]};
  const float* cb[3] = {(const float*)d_in[5],  (const float*)d_in[11], (const float*)d_in[17]};
  const float* sw[3] = {(const float*)d_in[6],  (const float*)d_in[12], (const float*)d_in[18]};
  const float* sb[3] = {(const float*)d_in[7],  (const float*)d_in[13], (const float*)d_in[19]};
  const float* kw[3] = {(const float*)d_in[8],  (const float*)d_in[14], (const float*)d_in[20]};
  const float* kb[3] = {(const float*)d_in[9],  (const float*)d_in[15], (const float*)d_in[21]};
  const float* fw = (const float*)d_in[22];
  const float* fb = (const float*)d_in[23];
  float* out = (float*)d_out;

  char* ws = (char*)d_ws;
  const size_t KB = 1024, MB = 1024 * 1024;
  float* disv               = (float*)(ws + 0);                   // 16 KB
  float* vT                 = (float*)(ws + 32 * KB);             // 16 KB
  unsigned long long* maskT = (unsigned long long*)(ws + 64 * KB);// 2 MB
  __hip_bfloat16* gHi       = (__hip_bfloat16*)(ws + 64 * KB + 2 * MB);            // 512 KB
  __hip_bfloat16* gLo       = (__hip_bfloat16*)(ws + 64 * KB + 2 * MB + 512 * KB); // 512 KB
  float* xselfT             = (float*)(ws + 64 * KB + 3 * MB);    // 1 MB
  float* xoutT              = (float*)(ws + 64 * KB + 4 * MB);    // 1 MB
  (void)in_sizes; (void)n_in; (void)out_size; (void)ws_size;

  k_prep<<<dim3(16, 16), 256, 0, stream>>>(K, maskT);
  k_xform0<<<64, 256, 0, stream>>>(K, maskT, cw[0], cb[0], sw[0], sb[0],
                                   disv, gHi, gLo, xselfT);
  k_agg<<<256, 512, 0, stream>>>(maskT, gHi, gLo, xselfT, disv, kw[0], kb[0], xoutT, vT);
  for (int l = 1; l < 3; ++l) {
    k_xform<<<dim3(64, 2), 320, 0, stream>>>(vT, xoutT, disv, cw[l], cb[l], sw[l], sb[l],
                                             gHi, gLo, xselfT);
    k_agg<<<256, 512, 0, stream>>>(maskT, gHi, gLo, xselfT, disv, kw[l], kb[l], xoutT, vT);
  }
  k_final<<<1, 512, 0, stream>>>(vT, xoutT, fw, fb, out);
}

// Round 11
// 198.119 us; speedup vs baseline: 1.1966x; 1.1899x over previous
//
#include <hip/hip_runtime.h>
#include <hip/hip_bf16.h>
#include <cstdint>
#include <cstddef>

#define NN 4096

typedef float f32x4 __attribute__((ext_vector_type(4)));
typedef short s16x8 __attribute__((ext_vector_type(8)));

// ---------- prep: bit-plane mask maskT[chunk][d] (bit i = row sbase+i); no atomics ----------
__global__ __launch_bounds__(256) void k_prep(const float* __restrict__ K,
                                              unsigned long long* __restrict__ maskT) {
  const int lane = threadIdx.x & 63;
  const int wv = threadIdx.x >> 6;
  const int d0 = blockIdx.x * 256 + lane * 4;      // each lane owns 4 columns
  const int sbase = blockIdx.y * 256 + wv * 64;    // this wave's 64-row chunk
  const int chunk = blockIdx.y * 4 + wv;
  unsigned long long w0 = 0, w1 = 0, w2 = 0, w3 = 0;
#pragma unroll 8
  for (int i = 0; i < 64; ++i) {
    const float4 kv = *(const float4*)(K + (size_t)(sbase + i) * NN + d0);
    w0 |= ((unsigned long long)(kv.x != 0.0f)) << i;
    w1 |= ((unsigned long long)(kv.y != 0.0f)) << i;
    w2 |= ((unsigned long long)(kv.z != 0.0f)) << i;
    w3 |= ((unsigned long long)(kv.w != 0.0f)) << i;
  }
  unsigned long long* mp = maskT + (size_t)chunk * NN + d0;
  mp[0] = w0; mp[1] = w1; mp[2] = w2; mp[3] = w3;
}

// ---------- 4-wave block-parallel Sinkhorn, potentials form ----------
// mat[r*65+c] = S0[r][c] (pre-scaled by 1/tau). Thread (w=tid>>6, l=tid&63):
// row pass: partial LSE of row l over cols w*16..w*16+15; col pass symmetric.
// All LDS patterns are 2-lanes/bank (free) or uniform broadcast.
// On exit mat = log-normalized matrix. MUST be called by all 256 threads.
__device__ __forceinline__ void sinkhorn_par4(float* __restrict__ mat,
    float* __restrict__ potU, float* __restrict__ potV,
    float* __restrict__ pmax, float* __restrict__ psum, int tid) {
  const int l = tid & 63;
  const int w = tid >> 6;            // 0..3
  const int jb = w * 16;
  if (w == 0) potV[l] = 0.f;
  __syncthreads();                   // also covers caller's staging writes
  for (int it = 0; it < 20; ++it) {
    const bool row = (it & 1) == 0;
    float x[16];
    if (row) {
#pragma unroll
      for (int j = 0; j < 16; ++j) x[j] = mat[l * 65 + jb + j] - potV[jb + j];
    } else {
#pragma unroll
      for (int j = 0; j < 16; ++j) x[j] = mat[(jb + j) * 65 + l] - potU[jb + j];
    }
    float mx = x[0];
#pragma unroll
    for (int j = 1; j < 16; ++j) mx = fmaxf(mx, x[j]);
    float sm = 0.f;
#pragma unroll
    for (int j = 0; j < 16; ++j) sm += __expf(x[j] - mx);
    pmax[w * 64 + l] = mx;
    psum[w * 64 + l] = sm;
    __syncthreads();
    if (w == 0) {                    // combine 4 partials -> LSE for row/col l
      const float m0 = pmax[l], m1 = pmax[64 + l], m2 = pmax[128 + l], m3 = pmax[192 + l];
      const float mM = fmaxf(fmaxf(m0, m1), fmaxf(m2, m3));
      const float ss = psum[l] * __expf(m0 - mM) + psum[64 + l] * __expf(m1 - mM)
                     + psum[128 + l] * __expf(m2 - mM) + psum[192 + l] * __expf(m3 - mM);
      const float lse = mM + __logf(ss);
      if (row) potU[l] = lse; else potV[l] = lse;
    }
    __syncthreads();
  }
  const float u = potU[l];
#pragma unroll
  for (int j = 0; j < 16; ++j)
    mat[l * 65 + jb + j] -= u + potV[jb + j];      // mat = S0 - U[i] - V[j]
  __syncthreads();
}

// ---------- layer-0 transform: deg from maskT popcounts, disv, g hi/lo, xselfT ----------
__global__ __launch_bounds__(256) void k_xform0(const float* __restrict__ K,
    const unsigned long long* __restrict__ maskT,
    const float* __restrict__ cw, const float* __restrict__ cb,
    const float* __restrict__ sw, const float* __restrict__ sb,
    float* __restrict__ disv,
    __hip_bfloat16* __restrict__ gHi, __hip_bfloat16* __restrict__ gLo,
    float* __restrict__ xselfT) {
  __shared__ float pdeg[4][64];
  const int lane = threadIdx.x & 63;
  const int wv = threadIdx.x >> 6;
  const int s = blockIdx.x * 64 + lane;
  unsigned cnt = 0;
#pragma unroll
  for (int q = 0; q < 16; ++q)
    cnt += (unsigned)__popcll(maskT[(size_t)(wv * 16 + q) * NN + s]);
  pdeg[wv][lane] = (float)cnt;
  __syncthreads();
  const float ds = rsqrtf(pdeg[0][lane] + pdeg[1][lane] + pdeg[2][lane] + pdeg[3][lane]);
  if (wv == 0) disv[s] = ds;
  const float xv = K[(size_t)s * NN + s];          // diag(K)
#pragma unroll
  for (int i = 0; i < 16; ++i) {
    const int c = wv * 16 + i;
    const float gv = ds * xv * cw[c];
    const __hip_bfloat16 hi = __float2bfloat16(gv);
    gHi[(size_t)c * NN + s] = hi;
    gLo[(size_t)c * NN + s] = __float2bfloat16(gv - __bfloat162float(hi));
    xselfT[(size_t)c * NN + s] = xv * sw[c] + sb[c] + cb[c];
  }
}

// ---------- layer transform: stage -> par4 sinkhorn -> FMA -> rank-1 sk fold ----------
// grid (64, 2): blockIdx.x = s-tile, blockIdx.y = 32-channel half. 256 threads.
__global__ __launch_bounds__(256, 1) void k_xform(const float* __restrict__ vT,
    const float* __restrict__ xoutT, const float* __restrict__ disv,
    const float* __restrict__ cw, const float* __restrict__ cb,
    const float* __restrict__ sw, const float* __restrict__ sb,
    __hip_bfloat16* __restrict__ gHi, __hip_bfloat16* __restrict__ gLo,
    float* __restrict__ xselfT) {
  __shared__ float skl[64 * 65];                   // sinkhorn matrix -> log sk
  __shared__ float xt[64][64];                     // raw xout
  __shared__ float wcl[64 * 32], wsl[64 * 32];     // [k][c-local]
  __shared__ float potU[64], potV[64], pmax[256], psum[256];
  const int tid = threadIdx.x;
  const int l = tid & 63;
  const int w = tid >> 6;                          // 0..3
  const int s = blockIdx.x * 64 + l;
  const int cbase = blockIdx.y * 32;
  // ---- stage (coalesced) ----
#pragma unroll
  for (int j = 0; j < 16; ++j)
    skl[l * 65 + w * 16 + j] = vT[(w * 16 + j) * 64 + l] * 20.0f;   // S0[l][j]
#pragma unroll
  for (int r = 0; r < 16; ++r)
    xt[w * 16 + r][l] = xoutT[(size_t)(w * 16 + r) * NN + s];
#pragma unroll
  for (int q = 0; q < 8; ++q) {
    const int e = w * 512 + q * 64 + l;            // e = k*32 + cl
    const int k = e >> 5, cl = e & 31;
    wcl[e] = cw[k * 64 + cbase + cl];
    wsl[e] = sw[k * 64 + cbase + cl];
  }
  // ---- block-parallel sinkhorn (entry barrier covers staging) ----
  sinkhorn_par4(skl, potU, potV, pmax, psum, tid);
  // ---- FMA: 8 channels per wave; float4 broadcast weight reads ----
  const int cl0 = w * 8;
  float accC[8], accS[8], csum[8], ssum[8];
#pragma unroll
  for (int i = 0; i < 8; ++i) { accC[i] = 0.f; accS[i] = 0.f; csum[i] = 0.f; ssum[i] = 0.f; }
  for (int k = 0; k < 64; ++k) {
    const float xv = xt[k][l];
    const f32x4 wcA = *(const f32x4*)&wcl[k * 32 + cl0];
    const f32x4 wcB = *(const f32x4*)&wcl[k * 32 + cl0 + 4];
    const f32x4 wsA = *(const f32x4*)&wsl[k * 32 + cl0];
    const f32x4 wsB = *(const f32x4*)&wsl[k * 32 + cl0 + 4];
#pragma unroll
    for (int i = 0; i < 4; ++i) {
      accC[i]     = fmaf(xv, wcA[i], accC[i]);     csum[i]     += wcA[i];
      accC[i + 4] = fmaf(xv, wcB[i], accC[i + 4]); csum[i + 4] += wcB[i];
      accS[i]     = fmaf(xv, wsA[i], accS[i]);     ssum[i]     += wsA[i];
      accS[i + 4] = fmaf(xv, wsB[i], accS[i + 4]); ssum[i + 4] += wsB[i];
    }
  }
  // ---- epilogue: rank-1 sk fold, bf16 hi/lo split ----
  const float skv = __expf(skl[blockIdx.x * 65 + l]);      // sk[s>>6][s&63]
  const float ds = disv[s];
#pragma unroll
  for (int i = 0; i < 8; ++i) {
    const int c = cbase + cl0 + i;
    const float gv = ds * (accC[i] + skv * csum[i]);
    const __hip_bfloat16 hi = __float2bfloat16(gv);
    gHi[(size_t)c * NN + s] = hi;
    gLo[(size_t)c * NN + s] = __float2bfloat16(gv - __bfloat162float(hi));
    xselfT[(size_t)c * NN + s] = accS[i] + skv * ssum[i] + sb[c] + cb[c];
  }
}

// ---------- MFMA masked aggregation, full K per block, in-block combine ----------
__global__ __launch_bounds__(512) void k_agg(const unsigned long long* __restrict__ maskT,
    const __hip_bfloat16* __restrict__ gHi, const __hip_bfloat16* __restrict__ gLo,
    const float* __restrict__ xselfT, const float* __restrict__ disv,
    const float* __restrict__ kw, const float* __restrict__ kb,
    float* __restrict__ xoutT, float* __restrict__ vT) {
  const int tid = threadIdx.x;
  const int lane = tid & 63;
  const int wv = tid >> 6;           // 0..7
  const int mtile = wv & 3;          // channel 16-group
  const int ks = wv >> 2;            // K-split 0/1
  const int l15 = lane & 15;
  const int h = lane >> 4;           // 0..3
  const int d = blockIdx.x * 16 + l15;
  const int ch = mtile * 16 + l15;   // A-operand row (channel)
  const short* __restrict__ gh = (const short*)gHi;
  const short* __restrict__ gl = (const short*)gLo;
  f32x4 acch = {0.f, 0.f, 0.f, 0.f};
  f32x4 accl = {0.f, 0.f, 0.f, 0.f};
  const int c0 = ks * 32;
#pragma unroll 4
  for (int c = c0; c < c0 + 32; ++c) {
    const unsigned long long w = maskT[(size_t)c * NN + d];
    const unsigned half0 = (unsigned)w, half1 = (unsigned)(w >> 32);
#pragma unroll
    for (int t = 0; t < 2; ++t) {
      const unsigned half = t ? half1 : half0;
      const unsigned hb = (half >> (8 * h)) & 0xFFu;
      s16x8 bfr;
#pragma unroll
      for (int j = 0; j < 8; ++j)
        bfr[j] = (short)(((hb >> j) & 1u) * 0x3F80u);   // bit -> bf16 1.0/0.0
      const size_t abase = (size_t)ch * NN + (size_t)(c * 64 + t * 32 + 8 * h);
      const s16x8 ah = *(const s16x8*)(gh + abase);
      const s16x8 al = *(const s16x8*)(gl + abase);
      acch = __builtin_amdgcn_mfma_f32_16x16x32_bf16(ah, bfr, acch, 0, 0, 0);
      accl = __builtin_amdgcn_mfma_f32_16x16x32_bf16(al, bfr, accl, 0, 0, 0);
    }
  }
  __shared__ float rbuf[4][64][5];
  __shared__ float vred[16][17];
  f32x4 tot;
#pragma unroll
  for (int r = 0; r < 4; ++r) tot[r] = acch[r] + accl[r];
  if (ks == 1) {
#pragma unroll
    for (int r = 0; r < 4; ++r) rbuf[mtile][lane][r] = tot[r];
  }
  __syncthreads();
  if (ks == 0) {
    // C/D layout: col = lane&15 (=d), row = (lane>>4)*4 + reg (=channel in mtile)
    const float dd = disv[d];
    float p = 0.f;
#pragma unroll
    for (int r = 0; r < 4; ++r) {
      const int chr = mtile * 16 + h * 4 + r;
      const float xo = xselfT[(size_t)chr * NN + d] + dd * (tot[r] + rbuf[mtile][lane][r]);
      xoutT[(size_t)chr * NN + d] = xo;
      p = fmaf(xo, kw[chr], p);
    }
    vred[l15][mtile * 4 + h] = p;
  }
  __syncthreads();
  if (tid < 16) {
    float sum = kb[0];
#pragma unroll
    for (int q = 0; q < 16; ++q) sum += vred[tid][q];
    const int d2 = blockIdx.x * 16 + tid;
    vT[(d2 & 63) * 64 + (d2 >> 6)] = sum;          // transposed: coalesced sinkhorn load
  }
}

// ---------- final: matvec (f4) -> par4 sinkhorn(sk2) -> fold -> par4 sinkhorn -> out ----------
__global__ __launch_bounds__(256, 1) void k_final(const float* __restrict__ vT,
    const float* __restrict__ xoutT, const float* __restrict__ fw,
    const float* __restrict__ fb, float* __restrict__ out) {
  __shared__ float skl[64 * 65];                   // sk2 matrix
  __shared__ float scp[64 * 65];                   // transposed scores matrix
  __shared__ float scfl[NN / 1];                   // flat scores (node order) -- 16 KB
  __shared__ float fwl[64];
  __shared__ float potU[64], potV[64], pmax[256], psum[256];
  const int tid = threadIdx.x;
  const int l = tid & 63;
  const int w = tid >> 6;
  // stage sk2 input + weights
#pragma unroll
  for (int j = 0; j < 16; ++j)
    skl[l * 65 + w * 16 + j] = vT[(w * 16 + j) * 64 + l] * 20.0f;
  if (tid < 64) fwl[tid] = fw[tid];
  __syncthreads();
  // phase A: scores base matvec (float4 over n)
  const float fbv = fb[0];
  float sumw = 0.f;
#pragma unroll
  for (int k = 0; k < 64; ++k) sumw += fwl[k];
#pragma unroll
  for (int g = 0; g < 4; ++g) {
    const int n0 = g * 1024 + tid * 4;
    f32x4 acc = {fbv, fbv, fbv, fbv};
    for (int k = 0; k < 64; ++k) {
      const f32x4 xv = *(const f32x4*)(xoutT + (size_t)k * NN + n0);
      const float fk = fwl[k];
#pragma unroll
      for (int i = 0; i < 4; ++i) acc[i] = fmaf(xv[i], fk, acc[i]);
    }
    *(f32x4*)&scfl[n0] = acc;
  }
  // sk2 (entry barrier covers scfl/phase A? -- scfl not read by sinkhorn; skl staged above)
  sinkhorn_par4(skl, potU, potV, pmax, psum, tid);
  // fold: scp[i1][i2] = (scores[n] + sk2[n]*sumw)/tau, i1=n&63, i2=n>>6
  for (int n = tid; n < NN; n += 256) {
    const float sk2 = __expf(skl[(n >> 6) * 65 + (n & 63)]);
    scp[(n & 63) * 65 + (n >> 6)] = (scfl[n] + sk2 * sumw) * 20.0f;
  }
  sinkhorn_par4(scp, potU, potV, pmax, psum, tid); // entry barrier covers fold
#pragma unroll
  for (int q = 0; q < 16; ++q) {
    const int e = q * 256 + tid;                   // out[i1*64+i2]
    out[e] = __expf(scp[(e >> 6) * 65 + (e & 63)]);
  }
}

extern "C" void kernel_launch(void* const* d_in, const int* in_sizes, int n_in,
                              void* d_out, int out_size, void* d_ws, size_t ws_size,
                              hipStream_t stream) {
  const float* K = (const float*)d_in[0];
  const float* cw[3] = {(const float*)d_in[4],  (const float*)d_in[10], (const float*)d_in[16]};
  const float* cb[3] = {(const float*)d_in[5],  (const float*)d_in[11], (const float*)d_in[17]};
  const float* sw[3] = {(const float*)d_in[6],  (const float*)d_in[12], (const float*)d_in[18]};
  const float* sb[3] = {(const float*)d_in[7],  (const float*)d_in[13], (const float*)d_in[19]};
  const float* kw[3] = {(const float*)d_in[8],  (const float*)d_in[14], (const float*)d_in[20]};
  const float* kb[3] = {(const float*)d_in[9],  (const float*)d_in[15], (const float*)d_in[21]};
  const float* fw = (const float*)d_in[22];
  const float* fb = (const float*)d_in[23];
  float* out = (float*)d_out;

  char* ws = (char*)d_ws;
  const size_t KB = 1024, MB = 1024 * 1024;
  float* disv               = (float*)(ws + 0);                   // 16 KB
  float* vT                 = (float*)(ws + 32 * KB);             // 16 KB
  unsigned long long* maskT = (unsigned long long*)(ws + 64 * KB);// 2 MB
  __hip_bfloat16* gHi       = (__hip_bfloat16*)(ws + 64 * KB + 2 * MB);            // 512 KB
  __hip_bfloat16* gLo       = (__hip_bfloat16*)(ws + 64 * KB + 2 * MB + 512 * KB); // 512 KB
  float* xselfT             = (float*)(ws + 64 * KB + 3 * MB);    // 1 MB
  float* xoutT              = (float*)(ws + 64 * KB + 4 * MB);    // 1 MB
  (void)in_sizes; (void)n_in; (void)out_size; (void)ws_size;

  k_prep<<<dim3(16, 16), 256, 0, stream>>>(K, maskT);
  k_xform0<<<64, 256, 0, stream>>>(K, maskT, cw[0], cb[0], sw[0], sb[0],
                                   disv, gHi, gLo, xselfT);
  k_agg<<<256, 512, 0, stream>>>(maskT, gHi, gLo, xselfT, disv, kw[0], kb[0], xoutT, vT);
  for (int l = 1; l < 3; ++l) {
    k_xform<<<dim3(64, 2), 256, 0, stream>>>(vT, xoutT, disv, cw[l], cb[l], sw[l], sb[l],
                                             gHi, gLo, xselfT);
    k_agg<<<256, 512, 0, stream>>>(maskT, gHi, gLo, xselfT, disv, kw[l], kb[l], xoutT, vT);
  }
  k_final<<<1, 256, 0, stream>>>(vT, xoutT, fw, fb, out);
}

// Round 12
// 189.376 us; speedup vs baseline: 1.2518x; 1.0462x over previous
//
#include <hip/hip_runtime.h>
#include <hip/hip_bf16.h>
#include <cstdint>
#include <cstddef>

#define NN 4096

typedef float f32x4 __attribute__((ext_vector_type(4)));
typedef short s16x8 __attribute__((ext_vector_type(8)));

// ---------- prep: bit-plane mask maskT[chunk][d] (bit i = row sbase+i); no atomics ----------
__global__ __launch_bounds__(256) void k_prep(const float* __restrict__ K,
                                              unsigned long long* __restrict__ maskT) {
  const int lane = threadIdx.x & 63;
  const int wv = threadIdx.x >> 6;
  const int d0 = blockIdx.x * 256 + lane * 4;      // each lane owns 4 columns
  const int sbase = blockIdx.y * 256 + wv * 64;    // this wave's 64-row chunk
  const int chunk = blockIdx.y * 4 + wv;
  unsigned long long w0 = 0, w1 = 0, w2 = 0, w3 = 0;
#pragma unroll 8
  for (int i = 0; i < 64; ++i) {
    const float4 kv = *(const float4*)(K + (size_t)(sbase + i) * NN + d0);
    w0 |= ((unsigned long long)(kv.x != 0.0f)) << i;
    w1 |= ((unsigned long long)(kv.y != 0.0f)) << i;
    w2 |= ((unsigned long long)(kv.z != 0.0f)) << i;
    w3 |= ((unsigned long long)(kv.w != 0.0f)) << i;
  }
  unsigned long long* mp = maskT + (size_t)chunk * NN + d0;
  mp[0] = w0; mp[1] = w1; mp[2] = w2; mp[3] = w3;
}

// ---------- 4-wave block-parallel Sinkhorn, potentials form ----------
// mat[r*65+c] = S0[r][c] (pre-scaled by 1/tau). Thread (w=tid>>6, l=tid&63):
// row pass: partial LSE of row l over cols w*16..w*16+15; col pass symmetric.
// On exit mat = log-normalized matrix. MUST be called by all 256 threads.
__device__ __forceinline__ void sinkhorn_par4(float* __restrict__ mat,
    float* __restrict__ potU, float* __restrict__ potV,
    float* __restrict__ pmax, float* __restrict__ psum, int tid) {
  const int l = tid & 63;
  const int w = tid >> 6;            // 0..3
  const int jb = w * 16;
  if (w == 0) potV[l] = 0.f;
  __syncthreads();                   // also covers caller's staging writes
  for (int it = 0; it < 20; ++it) {
    const bool row = (it & 1) == 0;
    float x[16];
    if (row) {
#pragma unroll
      for (int j = 0; j < 16; ++j) x[j] = mat[l * 65 + jb + j] - potV[jb + j];
    } else {
#pragma unroll
      for (int j = 0; j < 16; ++j) x[j] = mat[(jb + j) * 65 + l] - potU[jb + j];
    }
    float mx = x[0];
#pragma unroll
    for (int j = 1; j < 16; ++j) mx = fmaxf(mx, x[j]);
    float sm = 0.f;
#pragma unroll
    for (int j = 0; j < 16; ++j) sm += __expf(x[j] - mx);
    pmax[w * 64 + l] = mx;
    psum[w * 64 + l] = sm;
    __syncthreads();
    if (w == 0) {                    // combine 4 partials -> LSE for row/col l
      const float m0 = pmax[l], m1 = pmax[64 + l], m2 = pmax[128 + l], m3 = pmax[192 + l];
      const float mM = fmaxf(fmaxf(m0, m1), fmaxf(m2, m3));
      const float ss = psum[l] * __expf(m0 - mM) + psum[64 + l] * __expf(m1 - mM)
                     + psum[128 + l] * __expf(m2 - mM) + psum[192 + l] * __expf(m3 - mM);
      const float lse = mM + __logf(ss);
      if (row) potU[l] = lse; else potV[l] = lse;
    }
    __syncthreads();
  }
  const float u = potU[l];
#pragma unroll
  for (int j = 0; j < 16; ++j)
    mat[l * 65 + jb + j] -= u + potV[jb + j];      // mat = S0 - U[i] - V[j]
  __syncthreads();
}

// ---------- layer-0 transform: deg from maskT popcounts, disv, g hi/lo, xselfT ----------
__global__ __launch_bounds__(256) void k_xform0(const float* __restrict__ K,
    const unsigned long long* __restrict__ maskT,
    const float* __restrict__ cw, const float* __restrict__ cb,
    const float* __restrict__ sw, const float* __restrict__ sb,
    float* __restrict__ disv,
    __hip_bfloat16* __restrict__ gHi, __hip_bfloat16* __restrict__ gLo,
    float* __restrict__ xselfT) {
  __shared__ float pdeg[4][64];
  const int lane = threadIdx.x & 63;
  const int wv = threadIdx.x >> 6;
  const int s = blockIdx.x * 64 + lane;
  unsigned cnt = 0;
#pragma unroll
  for (int q = 0; q < 16; ++q)
    cnt += (unsigned)__popcll(maskT[(size_t)(wv * 16 + q) * NN + s]);
  pdeg[wv][lane] = (float)cnt;
  __syncthreads();
  const float ds = rsqrtf(pdeg[0][lane] + pdeg[1][lane] + pdeg[2][lane] + pdeg[3][lane]);
  if (wv == 0) disv[s] = ds;
  const float xv = K[(size_t)s * NN + s];          // diag(K)
#pragma unroll
  for (int i = 0; i < 16; ++i) {
    const int c = wv * 16 + i;
    const float gv = ds * xv * cw[c];
    const __hip_bfloat16 hi = __float2bfloat16(gv);
    gHi[(size_t)c * NN + s] = hi;
    gLo[(size_t)c * NN + s] = __float2bfloat16(gv - __bfloat162float(hi));
    xselfT[(size_t)c * NN + s] = xv * sw[c] + sb[c] + cb[c];
  }
}

// ---------- layer transform: stage -> par4 sinkhorn -> FMA -> rank-1 sk fold ----------
// grid (64, 2): blockIdx.x = s-tile, blockIdx.y = 32-channel half. 256 threads.
__global__ __launch_bounds__(256, 1) void k_xform(const float* __restrict__ vT,
    const float* __restrict__ xoutT, const float* __restrict__ disv,
    const float* __restrict__ cw, const float* __restrict__ cb,
    const float* __restrict__ sw, const float* __restrict__ sb,
    __hip_bfloat16* __restrict__ gHi, __hip_bfloat16* __restrict__ gLo,
    float* __restrict__ xselfT) {
  __shared__ float skl[64 * 65];                   // sinkhorn matrix -> log sk
  __shared__ float xt[64][64];                     // raw xout
  __shared__ float wcl[64 * 32], wsl[64 * 32];     // [k][c-local]
  __shared__ float potU[64], potV[64], pmax[256], psum[256];
  const int tid = threadIdx.x;
  const int l = tid & 63;
  const int w = tid >> 6;                          // 0..3
  const int s = blockIdx.x * 64 + l;
  const int cbase = blockIdx.y * 32;
  // ---- stage (coalesced) ----
#pragma unroll
  for (int j = 0; j < 16; ++j)
    skl[l * 65 + w * 16 + j] = vT[(w * 16 + j) * 64 + l] * 20.0f;   // S0[l][j]
#pragma unroll
  for (int r = 0; r < 16; ++r)
    xt[w * 16 + r][l] = xoutT[(size_t)(w * 16 + r) * NN + s];
#pragma unroll
  for (int q = 0; q < 8; ++q) {
    const int e = w * 512 + q * 64 + l;            // e = k*32 + cl
    const int k = e >> 5, cl = e & 31;
    wcl[e] = cw[k * 64 + cbase + cl];
    wsl[e] = sw[k * 64 + cbase + cl];
  }
  // ---- block-parallel sinkhorn (entry barrier covers staging) ----
  sinkhorn_par4(skl, potU, potV, pmax, psum, tid);
  // ---- FMA: 8 channels per wave; float4 broadcast weight reads ----
  const int cl0 = w * 8;
  float accC[8], accS[8], csum[8], ssum[8];
#pragma unroll
  for (int i = 0; i < 8; ++i) { accC[i] = 0.f; accS[i] = 0.f; csum[i] = 0.f; ssum[i] = 0.f; }
  for (int k = 0; k < 64; ++k) {
    const float xv = xt[k][l];
    const f32x4 wcA = *(const f32x4*)&wcl[k * 32 + cl0];
    const f32x4 wcB = *(const f32x4*)&wcl[k * 32 + cl0 + 4];
    const f32x4 wsA = *(const f32x4*)&wsl[k * 32 + cl0];
    const f32x4 wsB = *(const f32x4*)&wsl[k * 32 + cl0 + 4];
#pragma unroll
    for (int i = 0; i < 4; ++i) {
      accC[i]     = fmaf(xv, wcA[i], accC[i]);     csum[i]     += wcA[i];
      accC[i + 4] = fmaf(xv, wcB[i], accC[i + 4]); csum[i + 4] += wcB[i];
      accS[i]     = fmaf(xv, wsA[i], accS[i]);     ssum[i]     += wsA[i];
      accS[i + 4] = fmaf(xv, wsB[i], accS[i + 4]); ssum[i + 4] += wsB[i];
    }
  }
  // ---- epilogue: rank-1 sk fold, bf16 hi/lo split ----
  const float skv = __expf(skl[blockIdx.x * 65 + l]);      // sk[s>>6][s&63]
  const float ds = disv[s];
#pragma unroll
  for (int i = 0; i < 8; ++i) {
    const int c = cbase + cl0 + i;
    const float gv = ds * (accC[i] + skv * csum[i]);
    const __hip_bfloat16 hi = __float2bfloat16(gv);
    gHi[(size_t)c * NN + s] = hi;
    gLo[(size_t)c * NN + s] = __float2bfloat16(gv - __bfloat162float(hi));
    xselfT[(size_t)c * NN + s] = accS[i] + skv * ssum[i] + sb[c] + cb[c];
  }
}

// ---------- MFMA masked aggregation + in-block combine (+ final-score fold on last layer) ----------
__global__ __launch_bounds__(512) void k_agg(const unsigned long long* __restrict__ maskT,
    const __hip_bfloat16* __restrict__ gHi, const __hip_bfloat16* __restrict__ gLo,
    const float* __restrict__ xselfT, const float* __restrict__ disv,
    const float* __restrict__ kw, const float* __restrict__ kb,
    const float* __restrict__ fw, const float* __restrict__ fb,
    float* __restrict__ xoutT, float* __restrict__ vT, float* __restrict__ sbF) {
  const int tid = threadIdx.x;
  const int lane = tid & 63;
  const int wv = tid >> 6;           // 0..7
  const int mtile = wv & 3;          // channel 16-group
  const int ks = wv >> 2;            // K-split 0/1
  const int l15 = lane & 15;
  const int h = lane >> 4;           // 0..3
  const int d = blockIdx.x * 16 + l15;
  const int ch = mtile * 16 + l15;   // A-operand row (channel)
  const short* __restrict__ gh = (const short*)gHi;
  const short* __restrict__ gl = (const short*)gLo;
  f32x4 acch = {0.f, 0.f, 0.f, 0.f};
  f32x4 accl = {0.f, 0.f, 0.f, 0.f};
  const int c0 = ks * 32;
#pragma unroll 4
  for (int c = c0; c < c0 + 32; ++c) {
    const unsigned long long w = maskT[(size_t)c * NN + d];
    const unsigned half0 = (unsigned)w, half1 = (unsigned)(w >> 32);
#pragma unroll
    for (int t = 0; t < 2; ++t) {
      const unsigned half = t ? half1 : half0;
      const unsigned hb = (half >> (8 * h)) & 0xFFu;
      s16x8 bfr;
#pragma unroll
      for (int j = 0; j < 8; ++j)
        bfr[j] = (short)(((hb >> j) & 1u) * 0x3F80u);   // bit -> bf16 1.0/0.0
      const size_t abase = (size_t)ch * NN + (size_t)(c * 64 + t * 32 + 8 * h);
      const s16x8 ah = *(const s16x8*)(gh + abase);
      const s16x8 al = *(const s16x8*)(gl + abase);
      acch = __builtin_amdgcn_mfma_f32_16x16x32_bf16(ah, bfr, acch, 0, 0, 0);
      accl = __builtin_amdgcn_mfma_f32_16x16x32_bf16(al, bfr, accl, 0, 0, 0);
    }
  }
  __shared__ float rbuf[4][64][5];
  __shared__ float vred[16][17];
  __shared__ float vred2[16][17];
  f32x4 tot;
#pragma unroll
  for (int r = 0; r < 4; ++r) tot[r] = acch[r] + accl[r];
  if (ks == 1) {
#pragma unroll
    for (int r = 0; r < 4; ++r) rbuf[mtile][lane][r] = tot[r];
  }
  __syncthreads();
  if (ks == 0) {
    // C/D layout: col = lane&15 (=d), row = (lane>>4)*4 + reg (=channel in mtile)
    const float dd = disv[d];
    float p = 0.f, p2 = 0.f;
#pragma unroll
    for (int r = 0; r < 4; ++r) {
      const int chr = mtile * 16 + h * 4 + r;
      const float xo = xselfT[(size_t)chr * NN + d] + dd * (tot[r] + rbuf[mtile][lane][r]);
      xoutT[(size_t)chr * NN + d] = xo;
      p = fmaf(xo, kw[chr], p);
      p2 = fmaf(xo, fw[chr], p2);    // final-score partial (used only on last layer)
    }
    vred[l15][mtile * 4 + h] = p;
    vred2[l15][mtile * 4 + h] = p2;
  }
  __syncthreads();
  if (tid < 16) {
    float sum = kb[0];
#pragma unroll
    for (int q = 0; q < 16; ++q) sum += vred[tid][q];
    const int d2 = blockIdx.x * 16 + tid;
    vT[(d2 & 63) * 64 + (d2 >> 6)] = sum;          // transposed: coalesced sinkhorn load
    if (sbF != nullptr) {                          // last layer: base scores, flat
      float sum2 = fb[0];
#pragma unroll
      for (int q = 0; q < 16; ++q) sum2 += vred2[tid][q];
      sbF[d2] = sum2;
    }
  }
}

// ---------- final: pure-LDS. sinkhorn(sk2) -> fold -> sinkhorn -> out ----------
__global__ __launch_bounds__(256, 1) void k_final(const float* __restrict__ vT,
    const float* __restrict__ sbF, const float* __restrict__ fw,
    float* __restrict__ out) {
  __shared__ float skl[64 * 65];                   // sk2 matrix
  __shared__ float scp[64 * 65];                   // transposed scores matrix
  __shared__ float scfl[NN];                       // flat base scores -- 16 KB
  __shared__ float fwl[64];
  __shared__ float potU[64], potV[64], pmax[256], psum[256];
  const int tid = threadIdx.x;
  const int l = tid & 63;
  const int w = tid >> 6;
  // stage: sk2 input (coalesced), base scores (f32x4), fw
#pragma unroll
  for (int j = 0; j < 16; ++j)
    skl[l * 65 + w * 16 + j] = vT[(w * 16 + j) * 64 + l] * 20.0f;
#pragma unroll
  for (int q = 0; q < 4; ++q) {
    const int n0 = q * 1024 + tid * 4;
    *(f32x4*)&scfl[n0] = *(const f32x4*)&sbF[n0];
  }
  if (tid < 64) fwl[tid] = fw[tid];
  // sk2 sinkhorn (entry barrier covers staging)
  sinkhorn_par4(skl, potU, potV, pmax, psum, tid);
  float sumw = 0.f;
#pragma unroll
  for (int k = 0; k < 64; ++k) sumw += fwl[k];     // broadcast reads
  // fold: scp[i1][i2] = (scores[n] + sk2[n]*sumw)/tau, i1=n&63, i2=n>>6
  for (int n = tid; n < NN; n += 256) {
    const float sk2 = __expf(skl[(n >> 6) * 65 + (n & 63)]);
    scp[(n & 63) * 65 + (n >> 6)] = (scfl[n] + sk2 * sumw) * 20.0f;
  }
  sinkhorn_par4(scp, potU, potV, pmax, psum, tid); // entry barrier covers fold
#pragma unroll
  for (int q = 0; q < 16; ++q) {
    const int e = q * 256 + tid;                   // out[i1*64+i2]
    out[e] = __expf(scp[(e >> 6) * 65 + (e & 63)]);
  }
}

extern "C" void kernel_launch(void* const* d_in, const int* in_sizes, int n_in,
                              void* d_out, int out_size, void* d_ws, size_t ws_size,
                              hipStream_t stream) {
  const float* K = (const float*)d_in[0];
  const float* cw[3] = {(const float*)d_in[4],  (const float*)d_in[10], (const float*)d_in[16]};
  const float* cb[3] = {(const float*)d_in[5],  (const float*)d_in[11], (const float*)d_in[17]};
  const float* sw[3] = {(const float*)d_in[6],  (const float*)d_in[12], (const float*)d_in[18]};
  const float* sb[3] = {(const float*)d_in[7],  (const float*)d_in[13], (const float*)d_in[19]};
  const float* kw[3] = {(const float*)d_in[8],  (const float*)d_in[14], (const float*)d_in[20]};
  const float* kb[3] = {(const float*)d_in[9],  (const float*)d_in[15], (const float*)d_in[21]};
  const float* fw = (const float*)d_in[22];
  const float* fb = (const float*)d_in[23];
  float* out = (float*)d_out;

  char* ws = (char*)d_ws;
  const size_t KB = 1024, MB = 1024 * 1024;
  float* disv               = (float*)(ws + 0);                   // 16 KB
  float* vT                 = (float*)(ws + 32 * KB);             // 16 KB
  float* sbF                = (float*)(ws + 48 * KB);             // 16 KB
  unsigned long long* maskT = (unsigned long long*)(ws + 64 * KB);// 2 MB
  __hip_bfloat16* gHi       = (__hip_bfloat16*)(ws + 64 * KB + 2 * MB);            // 512 KB
  __hip_bfloat16* gLo       = (__hip_bfloat16*)(ws + 64 * KB + 2 * MB + 512 * KB); // 512 KB
  float* xselfT             = (float*)(ws + 64 * KB + 3 * MB);    // 1 MB
  float* xoutT              = (float*)(ws + 64 * KB + 4 * MB);    // 1 MB
  (void)in_sizes; (void)n_in; (void)out_size; (void)ws_size;

  k_prep<<<dim3(16, 16), 256, 0, stream>>>(K, maskT);
  k_xform0<<<64, 256, 0, stream>>>(K, maskT, cw[0], cb[0], sw[0], sb[0],
                                   disv, gHi, gLo, xselfT);
  k_agg<<<256, 512, 0, stream>>>(maskT, gHi, gLo, xselfT, disv, kw[0], kb[0],
                                 fw, fb, xoutT, vT, nullptr);
  for (int l = 1; l < 3; ++l) {
    k_xform<<<dim3(64, 2), 256, 0, stream>>>(vT, xoutT, disv, cw[l], cb[l], sw[l], sb[l],
                                             gHi, gLo, xselfT);
    k_agg<<<256, 512, 0, stream>>>(maskT, gHi, gLo, xselfT, disv, kw[l], kb[l],
                                   fw, fb, xoutT, vT, (l == 2) ? sbF : nullptr);
  }
  k_final<<<1, 256, 0, stream>>>(vT, sbF, fw, out);
}

// Round 13
// 188.427 us; speedup vs baseline: 1.2581x; 1.0050x over previous
//
#include <hip/hip_runtime.h>
#include <hip/hip_bf16.h>
#include <cstdint>
#include <cstddef>

#define NN 4096

typedef float f32x4 __attribute__((ext_vector_type(4)));
typedef short s16x8 __attribute__((ext_vector_type(8)));

// ---------- prep: bit-plane mask maskT[chunk][d] (bit i = row sbase+i); no atomics ----------
__global__ __launch_bounds__(256) void k_prep(const float* __restrict__ K,
                                              unsigned long long* __restrict__ maskT) {
  const int lane = threadIdx.x & 63;
  const int wv = threadIdx.x >> 6;
  const int d0 = blockIdx.x * 256 + lane * 4;      // each lane owns 4 columns
  const int sbase = blockIdx.y * 256 + wv * 64;    // this wave's 64-row chunk
  const int chunk = blockIdx.y * 4 + wv;
  unsigned long long w0 = 0, w1 = 0, w2 = 0, w3 = 0;
#pragma unroll 8
  for (int i = 0; i < 64; ++i) {
    const float4 kv = *(const float4*)(K + (size_t)(sbase + i) * NN + d0);
    w0 |= ((unsigned long long)(kv.x != 0.0f)) << i;
    w1 |= ((unsigned long long)(kv.y != 0.0f)) << i;
    w2 |= ((unsigned long long)(kv.z != 0.0f)) << i;
    w3 |= ((unsigned long long)(kv.w != 0.0f)) << i;
  }
  unsigned long long* mp = maskT + (size_t)chunk * NN + d0;
  mp[0] = w0; mp[1] = w1; mp[2] = w2; mp[3] = w3;
}

// ---------- 4-wave Sinkhorn, potentials form, vectorized LDS, NO writeback ----------
// matR[r*68+c] = matC[c*68+r] = S0[r][c] (pre-scaled by 1/tau). Stride 68: b128-aligned,
// granule slot = l mod 8 => conflict-free b128 in both orientations. 20 alternating LSE
// updates; on exit potU/potV hold the duals: log-normalized matrix = S0 - U[i] - V[j].
// MUST be called by all 256 threads; entry barrier covers caller staging.
__device__ __forceinline__ void sinkhorn_pots(const float* __restrict__ matR,
    const float* __restrict__ matC, float* __restrict__ potU, float* __restrict__ potV,
    float* __restrict__ pp, int tid) {
  const int l = tid & 63;
  const int w = tid >> 6;            // 0..3
  const int jb = w * 16;
  if (w == 0) potV[l] = 0.f;
  __syncthreads();
  for (int it = 0; it < 20; ++it) {
    const bool row = (it & 1) == 0;
    const float* src = row ? matR : matC;
    const float* pot = row ? potV : potU;
    f32x4 x0 = *(const f32x4*)&src[l * 68 + jb];
    f32x4 x1 = *(const f32x4*)&src[l * 68 + jb + 4];
    f32x4 x2 = *(const f32x4*)&src[l * 68 + jb + 8];
    f32x4 x3 = *(const f32x4*)&src[l * 68 + jb + 12];
    const f32x4 p0 = *(const f32x4*)&pot[jb];        // uniform b128 broadcast
    const f32x4 p1 = *(const f32x4*)&pot[jb + 4];
    const f32x4 p2 = *(const f32x4*)&pot[jb + 8];
    const f32x4 p3 = *(const f32x4*)&pot[jb + 12];
    x0 -= p0; x1 -= p1; x2 -= p2; x3 -= p3;
    f32x4 mA;
#pragma unroll
    for (int i = 0; i < 4; ++i)
      mA[i] = fmaxf(fmaxf(x0[i], x1[i]), fmaxf(x2[i], x3[i]));
    const float mx = fmaxf(fmaxf(mA[0], mA[1]), fmaxf(mA[2], mA[3]));
    float sm = 0.f;
#pragma unroll
    for (int i = 0; i < 4; ++i)
      sm += __expf(x0[i] - mx) + __expf(x1[i] - mx) +
            __expf(x2[i] - mx) + __expf(x3[i] - mx);
    pp[l * 12 + w] = mx;
    pp[l * 12 + 4 + w] = sm;
    __syncthreads();
    if (w == 0) {                    // combine 4 partials -> LSE for row/col l
      const f32x4 pm = *(const f32x4*)&pp[l * 12];
      const f32x4 ps = *(const f32x4*)&pp[l * 12 + 4];
      const float mM = fmaxf(fmaxf(pm[0], pm[1]), fmaxf(pm[2], pm[3]));
      const float ss = ps[0] * __expf(pm[0] - mM) + ps[1] * __expf(pm[1] - mM)
                     + ps[2] * __expf(pm[2] - mM) + ps[3] * __expf(pm[3] - mM);
      const float lse = mM + __logf(ss);
      (row ? potU : potV)[l] = lse;
    }
    __syncthreads();
  }
}

// ---------- layer-0 transform: deg from maskT popcounts, disv, g hi/lo, xselfT ----------
__global__ __launch_bounds__(256) void k_xform0(const float* __restrict__ K,
    const unsigned long long* __restrict__ maskT,
    const float* __restrict__ cw, const float* __restrict__ cb,
    const float* __restrict__ sw, const float* __restrict__ sb,
    float* __restrict__ disv,
    __hip_bfloat16* __restrict__ gHi, __hip_bfloat16* __restrict__ gLo,
    float* __restrict__ xselfT) {
  __shared__ float pdeg[4][64];
  const int lane = threadIdx.x & 63;
  const int wv = threadIdx.x >> 6;
  const int s = blockIdx.x * 64 + lane;
  unsigned cnt = 0;
#pragma unroll
  for (int q = 0; q < 16; ++q)
    cnt += (unsigned)__popcll(maskT[(size_t)(wv * 16 + q) * NN + s]);
  pdeg[wv][lane] = (float)cnt;
  __syncthreads();
  const float ds = rsqrtf(pdeg[0][lane] + pdeg[1][lane] + pdeg[2][lane] + pdeg[3][lane]);
  if (wv == 0) disv[s] = ds;
  const float xv = K[(size_t)s * NN + s];          // diag(K)
#pragma unroll
  for (int i = 0; i < 16; ++i) {
    const int c = wv * 16 + i;
    const float gv = ds * xv * cw[c];
    const __hip_bfloat16 hi = __float2bfloat16(gv);
    gHi[(size_t)c * NN + s] = hi;
    gLo[(size_t)c * NN + s] = __float2bfloat16(gv - __bfloat162float(hi));
    xselfT[(size_t)c * NN + s] = xv * sw[c] + sb[c] + cb[c];
  }
}

// ---------- layer transform: stage -> sinkhorn_pots -> FMA -> rank-1 sk fold ----------
// grid (64, 2): blockIdx.x = s-tile, blockIdx.y = 32-channel half. 256 threads.
__global__ __launch_bounds__(256, 1) void k_xform(const float* __restrict__ v,
    const float* __restrict__ vT,
    const float* __restrict__ xoutT, const float* __restrict__ disv,
    const float* __restrict__ cw, const float* __restrict__ cb,
    const float* __restrict__ sw, const float* __restrict__ sb,
    __hip_bfloat16* __restrict__ gHi, __hip_bfloat16* __restrict__ gLo,
    float* __restrict__ xselfT) {
  __shared__ __align__(16) float matR[64 * 68];    // S0 row-major (pre-scaled)
  __shared__ __align__(16) float matC[64 * 68];    // S0 col-major
  __shared__ float xt[64][64];                     // raw xout
  __shared__ float wcl[64 * 32], wsl[64 * 32];     // [k][c-local]
  __shared__ __align__(16) float potU[64], potV[64], pp[64 * 12];
  const int tid = threadIdx.x;
  const int l = tid & 63;
  const int w = tid >> 6;                          // 0..3
  const int jb = w * 16;
  const int s = blockIdx.x * 64 + l;
  const int cbase = blockIdx.y * 32;
  // ---- stage (f32x4 everywhere; LDS b128 writes conflict-free at stride 68) ----
#pragma unroll
  for (int q = 0; q < 4; ++q) {
    *(f32x4*)&matR[l * 68 + jb + 4 * q] = *(const f32x4*)&v[l * 64 + jb + 4 * q] * 20.0f;
    *(f32x4*)&matC[l * 68 + jb + 4 * q] = *(const f32x4*)&vT[l * 64 + jb + 4 * q] * 20.0f;
  }
#pragma unroll
  for (int r = 0; r < 16; ++r)
    xt[w * 16 + r][l] = xoutT[(size_t)(w * 16 + r) * NN + s];
#pragma unroll
  for (int q = 0; q < 8; ++q) {
    const int e = w * 512 + q * 64 + l;            // e = k*32 + cl
    const int k = e >> 5, cl = e & 31;
    wcl[e] = cw[k * 64 + cbase + cl];
    wsl[e] = sw[k * 64 + cbase + cl];
  }
  // ---- sinkhorn (entry barrier covers staging); duals left in potU/potV ----
  sinkhorn_pots(matR, matC, potU, potV, pp, tid);
  // ---- FMA: 8 channels per wave; float4 broadcast weight reads ----
  const int cl0 = w * 8;
  float accC[8], accS[8], csum[8], ssum[8];
#pragma unroll
  for (int i = 0; i < 8; ++i) { accC[i] = 0.f; accS[i] = 0.f; csum[i] = 0.f; ssum[i] = 0.f; }
  for (int k = 0; k < 64; ++k) {
    const float xv = xt[k][l];
    const f32x4 wcA = *(const f32x4*)&wcl[k * 32 + cl0];
    const f32x4 wcB = *(const f32x4*)&wcl[k * 32 + cl0 + 4];
    const f32x4 wsA = *(const f32x4*)&wsl[k * 32 + cl0];
    const f32x4 wsB = *(const f32x4*)&wsl[k * 32 + cl0 + 4];
#pragma unroll
    for (int i = 0; i < 4; ++i) {
      accC[i]     = fmaf(xv, wcA[i], accC[i]);     csum[i]     += wcA[i];
      accC[i + 4] = fmaf(xv, wcB[i], accC[i + 4]); csum[i + 4] += wcB[i];
      accS[i]     = fmaf(xv, wsA[i], accS[i]);     ssum[i]     += wsA[i];
      accS[i + 4] = fmaf(xv, wsB[i], accS[i + 4]); ssum[i + 4] += wsB[i];
    }
  }
  // ---- epilogue: sk value from duals, rank-1 sk fold, bf16 hi/lo split ----
  const float skv = __expf(matR[blockIdx.x * 68 + l] - potU[blockIdx.x] - potV[l]);
  const float ds = disv[s];
#pragma unroll
  for (int i = 0; i < 8; ++i) {
    const int c = cbase + cl0 + i;
    const float gv = ds * (accC[i] + skv * csum[i]);
    const __hip_bfloat16 hi = __float2bfloat16(gv);
    gHi[(size_t)c * NN + s] = hi;
    gLo[(size_t)c * NN + s] = __float2bfloat16(gv - __bfloat162float(hi));
    xselfT[(size_t)c * NN + s] = accS[i] + skv * ssum[i] + sb[c] + cb[c];
  }
}

// ---------- MFMA masked aggregation + in-block combine (+ final-score fold on last layer) ----------
__global__ __launch_bounds__(512) void k_agg(const unsigned long long* __restrict__ maskT,
    const __hip_bfloat16* __restrict__ gHi, const __hip_bfloat16* __restrict__ gLo,
    const float* __restrict__ xselfT, const float* __restrict__ disv,
    const float* __restrict__ kw, const float* __restrict__ kb,
    const float* __restrict__ fw, const float* __restrict__ fb,
    float* __restrict__ xoutT, float* __restrict__ v, float* __restrict__ vT,
    float* __restrict__ sbF) {
  const int tid = threadIdx.x;
  const int lane = tid & 63;
  const int wv = tid >> 6;           // 0..7
  const int mtile = wv & 3;          // channel 16-group
  const int ks = wv >> 2;            // K-split 0/1
  const int l15 = lane & 15;
  const int h = lane >> 4;           // 0..3
  const int d = blockIdx.x * 16 + l15;
  const int ch = mtile * 16 + l15;   // A-operand row (channel)
  const short* __restrict__ gh = (const short*)gHi;
  const short* __restrict__ gl = (const short*)gLo;
  f32x4 acch = {0.f, 0.f, 0.f, 0.f};
  f32x4 accl = {0.f, 0.f, 0.f, 0.f};
  const int c0 = ks * 32;
#pragma unroll 4
  for (int c = c0; c < c0 + 32; ++c) {
    const unsigned long long w = maskT[(size_t)c * NN + d];
    const unsigned half0 = (unsigned)w, half1 = (unsigned)(w >> 32);
#pragma unroll
    for (int t = 0; t < 2; ++t) {
      const unsigned half = t ? half1 : half0;
      const unsigned hb = (half >> (8 * h)) & 0xFFu;
      s16x8 bfr;
#pragma unroll
      for (int j = 0; j < 8; ++j)
        bfr[j] = (short)(((hb >> j) & 1u) * 0x3F80u);   // bit -> bf16 1.0/0.0
      const size_t abase = (size_t)ch * NN + (size_t)(c * 64 + t * 32 + 8 * h);
      const s16x8 ah = *(const s16x8*)(gh + abase);
      const s16x8 al = *(const s16x8*)(gl + abase);
      acch = __builtin_amdgcn_mfma_f32_16x16x32_bf16(ah, bfr, acch, 0, 0, 0);
      accl = __builtin_amdgcn_mfma_f32_16x16x32_bf16(al, bfr, accl, 0, 0, 0);
    }
  }
  __shared__ float rbuf[4][64][5];
  __shared__ float vred[16][17];
  __shared__ float vred2[16][17];
  f32x4 tot;
#pragma unroll
  for (int r = 0; r < 4; ++r) tot[r] = acch[r] + accl[r];
  if (ks == 1) {
#pragma unroll
    for (int r = 0; r < 4; ++r) rbuf[mtile][lane][r] = tot[r];
  }
  __syncthreads();
  if (ks == 0) {
    // C/D layout: col = lane&15 (=d), row = (lane>>4)*4 + reg (=channel in mtile)
    const float dd = disv[d];
    float p = 0.f, p2 = 0.f;
#pragma unroll
    for (int r = 0; r < 4; ++r) {
      const int chr = mtile * 16 + h * 4 + r;
      const float xo = xselfT[(size_t)chr * NN + d] + dd * (tot[r] + rbuf[mtile][lane][r]);
      xoutT[(size_t)chr * NN + d] = xo;
      p = fmaf(xo, kw[chr], p);
      p2 = fmaf(xo, fw[chr], p2);    // final-score partial (used only on last layer)
    }
    vred[l15][mtile * 4 + h] = p;
    vred2[l15][mtile * 4 + h] = p2;
  }
  __syncthreads();
  if (tid < 16) {
    float sum = kb[0];
#pragma unroll
    for (int q = 0; q < 16; ++q) sum += vred[tid][q];
    const int d2 = blockIdx.x * 16 + tid;
    v[d2] = sum;                                   // flat: row-major S0 staging
    vT[(d2 & 63) * 64 + (d2 >> 6)] = sum;          // transposed: col-major staging
    if (sbF != nullptr) {                          // last layer: base scores, flat
      float sum2 = fb[0];
#pragma unroll
      for (int q = 0; q < 16; ++q) sum2 += vred2[tid][q];
      sbF[d2] = sum2;
    }
  }
}

// ---------- final: pure-LDS. sinkhorn(sk2) -> fold -> sinkhorn -> out ----------
__global__ __launch_bounds__(256, 1) void k_final(const float* __restrict__ v,
    const float* __restrict__ vT, const float* __restrict__ sbF,
    const float* __restrict__ fw, float* __restrict__ out) {
  __shared__ __align__(16) float matR[64 * 68];    // sk2 S0 row-major
  __shared__ __align__(16) float matC[64 * 68];    // sk2 S0 col-major
  __shared__ __align__(16) float scR[64 * 68];     // final S row-major
  __shared__ __align__(16) float scT[64 * 68];     // final S col-major
  __shared__ float scfl[NN];                       // flat base scores -- 16 KB
  __shared__ float fwl[64];
  __shared__ __align__(16) float potU[64], potV[64], pp[64 * 12];
  const int tid = threadIdx.x;
  const int l = tid & 63;
  const int w = tid >> 6;
  const int jb = w * 16;
  // ---- stage sk2 matrices + base scores + fw ----
#pragma unroll
  for (int q = 0; q < 4; ++q) {
    *(f32x4*)&matR[l * 68 + jb + 4 * q] = *(const f32x4*)&v[l * 64 + jb + 4 * q] * 20.0f;
    *(f32x4*)&matC[l * 68 + jb + 4 * q] = *(const f32x4*)&vT[l * 64 + jb + 4 * q] * 20.0f;
  }
#pragma unroll
  for (int q = 0; q < 4; ++q) {
    const int n0 = q * 1024 + tid * 4;
    *(f32x4*)&scfl[n0] = *(const f32x4*)&sbF[n0];
  }
  if (tid < 64) fwl[tid] = fw[tid];
  // ---- sk2 sinkhorn (entry barrier covers staging) ----
  sinkhorn_pots(matR, matC, potU, potV, pp, tid);
  float sumw = 0.f;
#pragma unroll
  for (int k = 0; k < 64; ++k) sumw += fwl[k];     // broadcast reads
  // ---- fold: S[i1=n&63][i2=n>>6] = (scores[n] + sk2[n]*sumw)/tau ----
#pragma unroll
  for (int k = 0; k < 16; ++k) {
    const int n = k * 256 + tid;                   // i1 = l (col of sk2), row = 4k+w
    const int r2 = 4 * k + w;                      // n>>6 (uniform per wave-iter)
    const float sk2 = __expf(matR[r2 * 68 + l] - potU[r2] - potV[l]);
    const float val = (scfl[n] + sk2 * sumw) * 20.0f;
    scR[l * 68 + r2] = val;                        // S[l][r2]
    scT[r2 * 68 + l] = val;
  }
  __syncthreads();                                 // fold done before potV reset
  // ---- final sinkhorn ----
  sinkhorn_pots(scR, scT, potU, potV, pp, tid);
  // ---- output: out[i1*64+i2] = exp(S - U[i1] - V[i2]) ----
#pragma unroll
  for (int q = 0; q < 16; ++q) {
    const int e = q * 256 + tid;                   // i1 = 4q+w (uniform), i2 = l
    const int i1 = 4 * q + w;
    out[e] = __expf(scR[i1 * 68 + l] - potU[i1] - potV[l]);
  }
}

extern "C" void kernel_launch(void* const* d_in, const int* in_sizes, int n_in,
                              void* d_out, int out_size, void* d_ws, size_t ws_size,
                              hipStream_t stream) {
  const float* K = (const float*)d_in[0];
  const float* cw[3] = {(const float*)d_in[4],  (const float*)d_in[10], (const float*)d_in[16]};
  const float* cb[3] = {(const float*)d_in[5],  (const float*)d_in[11], (const float*)d_in[17]};
  const float* sw[3] = {(const float*)d_in[6],  (const float*)d_in[12], (const float*)d_in[18]};
  const float* sb[3] = {(const float*)d_in[7],  (const float*)d_in[13], (const float*)d_in[19]};
  const float* kw[3] = {(const float*)d_in[8],  (const float*)d_in[14], (const float*)d_in[20]};
  const float* kb[3] = {(const float*)d_in[9],  (const float*)d_in[15], (const float*)d_in[21]};
  const float* fw = (const float*)d_in[22];
  const float* fb = (const float*)d_in[23];
  float* out = (float*)d_out;

  char* ws = (char*)d_ws;
  const size_t KB = 1024, MB = 1024 * 1024;
  float* disv               = (float*)(ws + 0);                   // 16 KB
  float* v                  = (float*)(ws + 16 * KB);             // 16 KB
  float* vT                 = (float*)(ws + 32 * KB);             // 16 KB
  float* sbF                = (float*)(ws + 48 * KB);             // 16 KB
  unsigned long long* maskT = (unsigned long long*)(ws + 64 * KB);// 2 MB
  __hip_bfloat16* gHi       = (__hip_bfloat16*)(ws + 64 * KB + 2 * MB);            // 512 KB
  __hip_bfloat16* gLo       = (__hip_bfloat16*)(ws + 64 * KB + 2 * MB + 512 * KB); // 512 KB
  float* xselfT             = (float*)(ws + 64 * KB + 3 * MB);    // 1 MB
  float* xoutT              = (float*)(ws + 64 * KB + 4 * MB);    // 1 MB
  (void)in_sizes; (void)n_in; (void)out_size; (void)ws_size;

  k_prep<<<dim3(16, 16), 256, 0, stream>>>(K, maskT);
  k_xform0<<<64, 256, 0, stream>>>(K, maskT, cw[0], cb[0], sw[0], sb[0],
                                   disv, gHi, gLo, xselfT);
  k_agg<<<256, 512, 0, stream>>>(maskT, gHi, gLo, xselfT, disv, kw[0], kb[0],
                                 fw, fb, xoutT, v, vT, nullptr);
  for (int l = 1; l < 3; ++l) {
    k_xform<<<dim3(64, 2), 256, 0, stream>>>(v, vT, xoutT, disv, cw[l], cb[l], sw[l], sb[l],
                                             gHi, gLo, xselfT);
    k_agg<<<256, 512, 0, stream>>>(maskT, gHi, gLo, xselfT, disv, kw[l], kb[l],
                                   fw, fb, xoutT, v, vT, (l == 2) ? sbF : nullptr);
  }
  k_final<<<1, 256, 0, stream>>>(v, vT, sbF, fw, out);
}